// Round 11
// baseline (210.131 us; speedup 1.0000x reference)
//
#include <hip/hip_runtime.h>
#include <cstdint>
#include <cstddef>

// Low-rank bilinear attention, MI355X/gfx950.
// out = softmax((x@W1)(W2@x^T)/sqrt(512)) @ x,  x:[16,2048,512] fp32.
// Round 11: prep collapsed to ONE kernel (kw merged into k01; W-fragments
// computed inline per-dc with kw's exact masked-load math), and k01's staging
// software-pipelined R6-style: dc+1 loads issued after the xs-visible barrier,
// flying under transpose+factor compute, drained at the next top barrier.
// k3: round-6 winner, verbatim (85.6us, MfmaUtil 39).

typedef float    f32x4 __attribute__((ext_vector_type(4)));
typedef _Float16 half8 __attribute__((ext_vector_type(8)));
typedef _Float16 half4 __attribute__((ext_vector_type(4)));

#define B_  16
#define A_  2048
#define D_  512
#define KSCALE 0.06375872f   // (1/sqrt(512)) * log2(e)

#define SCHED_FENCE() __builtin_amdgcn_sched_barrier(0)

__device__ inline float fast_exp2(float v) {
#if __has_builtin(__builtin_amdgcn_exp2f)
    return __builtin_amdgcn_exp2f(v);
#else
    return __expf(v * 0.6931471805599453f);
#endif
}

// ---------------- k01: transpose + factors, x read once, W inline ----------------
// grid 1024 = (b:16, grp:64 of 32c); block 256 = 4 tiles x 2 kki waves.
// Pipelined: per dc, [B1: drain dc loads][store xs][B2][issue dc+1 loads]
// [transpose-out][factor MFMAs][wf(dc+1) compute] -- dc+1 loads fly under compute.
__global__ __launch_bounds__(256) void k01_prep(const float* __restrict__ x,
                                                const float* __restrict__ W1,
                                                const float* __restrict__ W2,
                                                _Float16* __restrict__ xT,
                                                _Float16* __restrict__ left16,
                                                _Float16* __restrict__ rightT16) {
    __shared__ float xs[32 * 64];
    int t = threadIdx.x, lane = t & 63, w = t >> 6;
    int quad = lane >> 4, c16 = lane & 15;
    int bid = blockIdx.x;
    int b = bid >> 6, grp = bid & 63;
    int c0 = grp << 5;
    const float* xb = x + ((size_t)b * A_ + c0) * D_;
    int tile = w >> 1, kki = w & 1;
    int ar = tile * 16 + c16;
    int col = c16;
    f32x4 accA = {0.f, 0.f, 0.f, 0.f}, accB = {0.f, 0.f, 0.f, 0.f};

    // staging addresses (p=0,1)
    int cA = (t >> 4), cB = 16 + (t >> 4), ch = t & 15;
    const float* srcA = xb + (size_t)cA * D_ + ch * 4;
    const float* srcB = xb + (size_t)cB * D_ + ch * 4;
    int dstA = cA * 64 + ((ch ^ (cA & 15)) << 2);
    int dstB = cB * 64 + ((ch ^ (cB & 15)) << 2);

    // inline W-fragment compute for K-tile kt (= dc*2+kki), kw's exact math
    auto wf_make = [&](int kt, half8& h1, half8& h2) {
        int dbase = kt * 32 + quad * 8;
#pragma unroll
        for (int j = 0; j < 8; ++j) {
            int d = dbase + j;
            h1[j] = (col < 10) ? (_Float16)(W1[d * 10 + col] * KSCALE) : (_Float16)0.f;
            h2[j] = (col < 10) ? (_Float16)W2[col * 512 + d] : (_Float16)0.f;
        }
    };

    // ---- prologue: loads + W-frags for dc=0 ----
    float4 rA = *(const float4*)(srcA);
    float4 rB = *(const float4*)(srcB);
    half8 wf1c, wf2c, wf1n, wf2n;
    wf_make(kki, wf1c, wf2c);

    for (int dc = 0; dc < 8; ++dc) {
        __syncthreads();                       // B1: drains dc-loads (flew under dc-1 compute)
        *(float4*)&xs[dstA] = rA;
        *(float4*)&xs[dstB] = rB;
        __syncthreads();                       // B2: xs visible to all waves
        if (dc < 7) {                          // issue dc+1 loads NOW -> fly under compute
            rA = *(const float4*)(srcA + (dc + 1) * 64);
            rB = *(const float4*)(srcB + (dc + 1) * 64);
        }
        SCHED_FENCE();
        {                                      // transpose out: half8 per thread
            int dloc = t >> 2, c8 = (t & 3) << 3;
            int chh = dloc >> 2, e = dloc & 3;
            half8 h;
#pragma unroll
            for (int j = 0; j < 8; ++j) {
                int c = c8 + j;
                h[j] = (_Float16)xs[c * 64 + ((chh ^ (c & 15)) << 2) + e];
            }
            *(half8*)(xT + ((size_t)b * D_ + dc * 64 + dloc) * A_ + c0 + c8) = h;
        }
        {                                      // factor MFMAs (wf for this dc, prefetched)
            int kk = kki * 32;
            int ch0 = (kk >> 2) + quad * 2;
            float4 v0 = *(const float4*)&xs[ar * 64 + ((ch0 ^ c16) << 2)];
            float4 v1 = *(const float4*)&xs[ar * 64 + (((ch0 + 1) ^ c16) << 2)];
            half8 af;
            af[0] = (_Float16)v0.x; af[1] = (_Float16)v0.y; af[2] = (_Float16)v0.z; af[3] = (_Float16)v0.w;
            af[4] = (_Float16)v1.x; af[5] = (_Float16)v1.y; af[6] = (_Float16)v1.z; af[7] = (_Float16)v1.w;
            accA = __builtin_amdgcn_mfma_f32_16x16x32_f16(af, wf1c, accA, 0, 0, 0);
            accB = __builtin_amdgcn_mfma_f32_16x16x32_f16(af, wf2c, accB, 0, 0, 0);
        }
        if (dc < 7) {                          // W-frags for dc+1 (L2-hit, drains at next B1)
            wf_make((dc + 1) * 2 + kki, wf1n, wf2n);
            wf1c = wf1n; wf2c = wf2n;
        }
    }
    __syncthreads();
    float* red = xs;
    if (kki == 0) {
#pragma unroll
        for (int q = 0; q < 4; ++q) {
            red[tile * 512 + (quad * 4 + q) * 16 + c16] = accA[q];
            red[tile * 512 + 256 + (quad * 4 + q) * 16 + c16] = accB[q];
        }
    }
    __syncthreads();
    if (kki == 1) {
#pragma unroll
        for (int q = 0; q < 4; ++q) {
            float a = accA[q] + red[tile * 512 + (quad * 4 + q) * 16 + c16];
            float bb = accB[q] + red[tile * 512 + 256 + (quad * 4 + q) * 16 + c16];
            size_t grow = (size_t)bid * 32 + tile * 16 + quad * 4 + q;
            left16[grow * 16 + c16] = (_Float16)a;     // cols 10..15 exact 0
            rightT16[grow * 16 + c16] = (_Float16)bb;  // cols 10..15 exact 0
        }
    }
}

// ------------- k3: pipelined fused P-recompute + softmax + (P@x) GEMM -------------
// 128a x 256d block tile, 512 thr / 8 waves (2M x 4N, 64a x 64d each), BK=32,
// grid 512 (XCD-swizzled), 1 barrier/iter, 2 blocks/CU, 4 waves/SIMD.
// Interleaved schedule per iter: [P-MFMA(k+1) | DMA(k+1) | bfr(k+2) | bf+af0]
//   fence [af1|mi0|exp0] fence [af2|mi1|exp1] fence [af3|mi2|writePs0]
//   fence [mi3|writePs1|bfr copy].   (round-6 winner, verbatim)
__global__ __launch_bounds__(512, 4) void k3_attn(const _Float16* __restrict__ xT,
                                                  const _Float16* __restrict__ left16,
                                                  const _Float16* __restrict__ rightT16,
                                                  float* __restrict__ out) {
    __shared__ _Float16 XTl[2][256 * 32];  // [buf][d-local][c-chunk swizzled], rows 64B (32 KB)
    __shared__ _Float16 Ps[2][128 * 40];   // [buf][a-local][c], stride 40 halfs (20.5 KB)
    __shared__ float rowsum[128];
    int t = threadIdx.x, lane = t & 63, w = t >> 6;   // w in [0,8)
    int quad = lane >> 4, c16 = lane & 15;
    int bid = blockIdx.x;
    int combo = (bid & 7) | (((bid >> 7) & 3) << 3);  // (b,nb) pinned per XCD (4 combos/XCD)
    int at = (bid >> 3) & 15;
    int b = combo >> 1, nb = combo & 1;
    int a0 = at << 7, n0 = nb << 8;
    int waveM = w & 1, waveN = w >> 1;                // 2 x 4

    // P fragment: lf8 = left B-operand for this wave's a-rows (quads 2,3 zero pad)
    half8 lf8 = (half8)(_Float16)0.f;
    if (quad < 2) {
        int arow = a0 + w * 16 + c16;
        lf8 = *(const half8*)(left16 + ((size_t)(b << 11) + arow) * 16 + quad * 8);
    }

    f32x4 acc[4][4];
#pragma unroll
    for (int mi = 0; mi < 4; ++mi)
#pragma unroll
        for (int ni = 0; ni < 4; ++ni) acc[mi][ni] = (f32x4){0.f, 0.f, 0.f, 0.f};
    float psum = 0.f;

    const _Float16* xTb = xT + ((size_t)b * D_ + n0) * A_;
    const _Float16* rTb = rightT16 + (size_t)(b << 11) * 16;

    int nloc0 = w * 32 + (lane >> 2);
    int kq = lane & 3;
    int psrow = (w * 16 + c16) * 40;                  // this wave's Ps row offset

    auto dma_tile = [&](int kt, int buf) {
        int c0 = kt << 5;
#pragma unroll
        for (int cc = 0; cc < 2; ++cc) {
            int nl = nloc0 + cc * 16;
            int kqs = kq ^ ((nl >> 1) & 3);
            const _Float16* src = xTb + (size_t)nl * A_ + c0 + kqs * 8;
            _Float16* dst = &XTl[buf][(w * 32 + cc * 16) * 32];
            __builtin_amdgcn_global_load_lds((const __attribute__((address_space(1))) void*)src,
                                             (__attribute__((address_space(3))) void*)dst,
                                             16, 0, 0);
        }
    };
    auto load_bfr = [&](int kt, half8* bfr) {
#pragma unroll
        for (int nh = 0; nh < 2; ++nh) {
            bfr[nh] = (half8)(_Float16)0.f;
            if (quad < 2) {
                int crow = (kt << 5) + nh * 16 + c16;
                bfr[nh] = *(const half8*)(rTb + (size_t)crow * 16 + quad * 8);
            }
        }
    };

    // ---- prologue: P(0) full, DMA(0), bfr for tile 1 ----
    half8 bfr_cur[2], bfr_nxt[2];
    load_bfr(0, bfr_cur);
    dma_tile(0, 0);
    {
        f32x4 zz = {0.f, 0.f, 0.f, 0.f};
        f32x4 p0 = __builtin_amdgcn_mfma_f32_16x16x32_f16(bfr_cur[0], lf8, zz, 0, 0, 0);
        f32x4 p1 = __builtin_amdgcn_mfma_f32_16x16x32_f16(bfr_cur[1], lf8, zz, 0, 0, 0);
        float e0 = fast_exp2(p0[0]), e1 = fast_exp2(p0[1]), e2 = fast_exp2(p0[2]), e3 = fast_exp2(p0[3]);
        float f0 = fast_exp2(p1[0]), f1 = fast_exp2(p1[1]), f2 = fast_exp2(p1[2]), f3 = fast_exp2(p1[3]);
        psum += (e0 + e1) + (e2 + e3) + (f0 + f1) + (f2 + f3);
        half4 pv0, pv1;
        pv0[0] = (_Float16)e0; pv0[1] = (_Float16)e1; pv0[2] = (_Float16)e2; pv0[3] = (_Float16)e3;
        pv1[0] = (_Float16)f0; pv1[1] = (_Float16)f1; pv1[2] = (_Float16)f2; pv1[3] = (_Float16)f3;
        *(half4*)&Ps[0][psrow + quad * 4] = pv0;
        *(half4*)&Ps[0][psrow + 16 + quad * 4] = pv1;
    }
    load_bfr(1, bfr_cur);   // tile 1 operand, consumed at iter 0

    // ---- main loop: iters 0..62 (full), iter 63 peeled (GEMM only) ----
    for (int kt = 0; kt < 63; ++kt) {
        __syncthreads();
        int cb = kt & 1, nx = kt + 1;

        // R0: P-MFMAs for tile nx; issue DMA(nx) + bfr(kt+2); bf + af0 reads
        f32x4 zz = {0.f, 0.f, 0.f, 0.f};
        f32x4 pc0 = __builtin_amdgcn_mfma_f32_16x16x32_f16(bfr_cur[0], lf8, zz, 0, 0, 0);
        f32x4 pc1 = __builtin_amdgcn_mfma_f32_16x16x32_f16(bfr_cur[1], lf8, zz, 0, 0, 0);
        dma_tile(nx, nx & 1);
        {
            int ktn = (kt + 2 < 64) ? kt + 2 : 0;    // branchless tail: dummy reload of tile 0
            load_bfr(ktn, bfr_nxt);
        }
        half8 bf[4];
#pragma unroll
        for (int ni = 0; ni < 4; ++ni) {
            int nr = waveN * 64 + ni * 16 + c16;
            bf[ni] = *(const half8*)&XTl[cb][nr * 32 + ((quad ^ ((nr >> 1) & 3)) << 3)];
        }
        half8 af0 = *(const half8*)&Ps[cb][(waveM * 64 + c16) * 40 + quad * 8];
        SCHED_FENCE();

        // R1: af1 read | mi0 cluster | exp chunk 0
        half8 af1 = *(const half8*)&Ps[cb][(waveM * 64 + 16 + c16) * 40 + quad * 8];
#pragma unroll
        for (int ni = 0; ni < 4; ++ni)
            acc[0][ni] = __builtin_amdgcn_mfma_f32_16x16x32_f16(af0, bf[ni], acc[0][ni], 0, 0, 0);
        float e0 = fast_exp2(pc0[0]), e1 = fast_exp2(pc0[1]);
        float e2 = fast_exp2(pc0[2]), e3 = fast_exp2(pc0[3]);
        psum += (e0 + e1) + (e2 + e3);
        half4 pv0;
        pv0[0] = (_Float16)e0; pv0[1] = (_Float16)e1; pv0[2] = (_Float16)e2; pv0[3] = (_Float16)e3;
        SCHED_FENCE();

        // R2: af2 read | mi1 cluster | exp chunk 1
        half8 af2 = *(const half8*)&Ps[cb][(waveM * 64 + 32 + c16) * 40 + quad * 8];
#pragma unroll
        for (int ni = 0; ni < 4; ++ni)
            acc[1][ni] = __builtin_amdgcn_mfma_f32_16x16x32_f16(af1, bf[ni], acc[1][ni], 0, 0, 0);
        float f0 = fast_exp2(pc1[0]), f1 = fast_exp2(pc1[1]);
        float f2 = fast_exp2(pc1[2]), f3 = fast_exp2(pc1[3]);
        psum += (f0 + f1) + (f2 + f3);
        half4 pv1;
        pv1[0] = (_Float16)f0; pv1[1] = (_Float16)f1; pv1[2] = (_Float16)f2; pv1[3] = (_Float16)f3;
        SCHED_FENCE();

        // R3: af3 read | mi2 cluster | Ps write 0
        half8 af3 = *(const half8*)&Ps[cb][(waveM * 64 + 48 + c16) * 40 + quad * 8];
#pragma unroll
        for (int ni = 0; ni < 4; ++ni)
            acc[2][ni] = __builtin_amdgcn_mfma_f32_16x16x32_f16(af2, bf[ni], acc[2][ni], 0, 0, 0);
        *(half4*)&Ps[nx & 1][psrow + quad * 4] = pv0;
        SCHED_FENCE();

        // R4: mi3 cluster | Ps write 1 | bfr rotate
#pragma unroll
        for (int ni = 0; ni < 4; ++ni)
            acc[3][ni] = __builtin_amdgcn_mfma_f32_16x16x32_f16(af3, bf[ni], acc[3][ni], 0, 0, 0);
        *(half4*)&Ps[nx & 1][psrow + 16 + quad * 4] = pv1;
        bfr_cur[0] = bfr_nxt[0];
        bfr_cur[1] = bfr_nxt[1];
    }

    // ---- peeled iter 63: GEMM only ----
    __syncthreads();
    {
        const int cb = 1;
        half8 bf[4];
#pragma unroll
        for (int ni = 0; ni < 4; ++ni) {
            int nr = waveN * 64 + ni * 16 + c16;
            bf[ni] = *(const half8*)&XTl[cb][nr * 32 + ((quad ^ ((nr >> 1) & 3)) << 3)];
        }
#pragma unroll
        for (int mi = 0; mi < 4; ++mi) {
            half8 af = *(const half8*)&Ps[cb][(waveM * 64 + mi * 16 + c16) * 40 + quad * 8];
#pragma unroll
            for (int ni = 0; ni < 4; ++ni)
                acc[mi][ni] = __builtin_amdgcn_mfma_f32_16x16x32_f16(af, bf[ni], acc[mi][ni], 0, 0, 0);
        }
    }

    // softmax denominators: psum holds partial row-sum for a-row w*16 + c16
    {
        float s = psum;
        s += __shfl_xor(s, 16);
        s += __shfl_xor(s, 32);
        if (quad == 0) rowsum[w * 16 + c16] = s;
    }
    __syncthreads();

    float* ob = out + ((size_t)b * A_ + a0) * D_ + n0;
#pragma unroll
    for (int mi = 0; mi < 4; ++mi) {
#pragma unroll
        for (int q = 0; q < 4; ++q) {
            int ar = waveM * 64 + mi * 16 + quad * 4 + q;
            float sc = 1.0f / rowsum[ar];
#pragma unroll
            for (int ni = 0; ni < 4; ++ni)
                ob[(size_t)ar * D_ + waveN * 64 + ni * 16 + c16] = acc[mi][ni][q] * sc;
        }
    }
}

extern "C" void kernel_launch(void* const* d_in, const int* in_sizes, int n_in,
                              void* d_out, int out_size, void* d_ws, size_t ws_size,
                              hipStream_t stream) {
    const float* x  = (const float*)d_in[0];
    const float* W1 = (const float*)d_in[1];
    const float* W2 = (const float*)d_in[2];
    float* out = (float*)d_out;
    char* ws = (char*)d_ws;
    // ws: xT f16 [16][512][2048] @0 (33,554,432)
    //     left16 f16 [32768][16] @33,554,432 (1,048,576)
    //     rightT16 f16 [32768][16] @34,603,008 (1,048,576)
    //     (Wf slot no longer used; kw merged into k01)
    _Float16* xT      = (_Float16*)ws;
    _Float16* left16  = (_Float16*)(ws + 33554432);
    _Float16* rightT16= (_Float16*)(ws + 34603008);

    k01_prep<<<1024, 256, 0, stream>>>(x, W1, W2, xT, left16, rightT16);
    k3_attn<<<512, 512, 0, stream>>>(xT, left16, rightT16, out);
}

// Round 12
// 201.665 us; speedup vs baseline: 1.0420x; 1.0420x over previous
//
#include <hip/hip_runtime.h>
#include <cstdint>
#include <cstddef>

// Low-rank bilinear attention, MI355X/gfx950.
// out = softmax((x@W1)(W2@x^T)/sqrt(512)) @ x,  x:[16,2048,512] fp32.
// FINAL (session-best, round-6 configuration verbatim, 205.66us verified):
// kw:  W1/W2 -> B-fragment f16 table (W1 pre-scaled by log2e/sqrt(512)).
// kt:  pure transpose x -> xT f16 [b][d][c], async DMA staging, 1 barrier/block.
// kf:  factor GEMM (left16/rightT16, stride-16 zero-padded) re-reading L3-warm x.
// k3:  128a x 256d, 8 waves, 2 blocks/CU, 1 barrier/iter, P/main interleaved
//      via sched_barrier regions; P-MFMA fed by bfr loaded one iter ahead.

typedef float    f32x4 __attribute__((ext_vector_type(4)));
typedef _Float16 half8 __attribute__((ext_vector_type(8)));
typedef _Float16 half4 __attribute__((ext_vector_type(4)));

#define B_  16
#define A_  2048
#define D_  512
#define KSCALE 0.06375872f   // (1/sqrt(512)) * log2(e)

#define SCHED_FENCE() __builtin_amdgcn_sched_barrier(0)

__device__ inline float fast_exp2(float v) {
#if __has_builtin(__builtin_amdgcn_exp2f)
    return __builtin_amdgcn_exp2f(v);
#else
    return __expf(v * 0.6931471805599453f);
#endif
}

// ---- kw: Wf[kt(16)][lane(64)][2 factors][half8]  (32 KB, L2-resident) ----
__global__ __launch_bounds__(256) void kw_prep(const float* __restrict__ W1,
                                               const float* __restrict__ W2,
                                               _Float16* __restrict__ Wf) {
    int pi = blockIdx.x * 256 + threadIdx.x;   // (kt, lane), 1024 total
    int kt = pi >> 6, lane = pi & 63;
    int quad = lane >> 4, col = lane & 15;
    half8 h1, h2;
#pragma unroll
    for (int j = 0; j < 8; ++j) {
        int d = kt * 32 + quad * 8 + j;
        h1[j] = (col < 10) ? (_Float16)(W1[d * 10 + col] * KSCALE) : (_Float16)0.f;
        h2[j] = (col < 10) ? (_Float16)W2[col * 512 + d] : (_Float16)0.f;  // col<10: W2 has 10 rows
    }
    *(half8*)(Wf + (size_t)pi * 16) = h1;
    *(half8*)(Wf + (size_t)pi * 16 + 8) = h2;
}

// ---------------- kt: pure transpose x fp32 [b][c][d] -> xT f16 [b][d][c] ----------------
// grid 2048 = (b:16, cg:16 of 128c, dg:8 of 64d); block 256; LDS 32 KB, 1 barrier.
__global__ __launch_bounds__(256) void kt_transpose(const float* __restrict__ x,
                                                    _Float16* __restrict__ xT) {
    __shared__ float xs[128 * 64];
    int t = threadIdx.x, w = t >> 6;
    int bid = blockIdx.x;
    int b = bid >> 7, cg = (bid >> 3) & 15, dg = bid & 7;
    int c0 = cg << 7, d0 = dg << 6;
    const float* xb = x + ((size_t)(b * A_ + c0)) * D_ + d0;
#pragma unroll
    for (int it = 0; it < 8; ++it) {
        int slot = it * 256 + t;
        int c = slot >> 4, g = slot & 15;
        int gs = g ^ (c >> 3);                       // source-side XOR swizzle (16B granules)
        const float* src = xb + (size_t)c * D_ + (gs << 2);
        float* dst = xs + (size_t)(it * 256 + w * 64) * 4;   // wave-uniform base, lane*16B appended by HW
        __builtin_amdgcn_global_load_lds((const __attribute__((address_space(1))) void*)src,
                                         (__attribute__((address_space(3))) void*)dst,
                                         16, 0, 0);
    }
    __syncthreads();   // drains vmcnt before LDS reads
    _Float16* xTb = xT + ((size_t)b * D_ + d0) * A_ + c0;
#pragma unroll
    for (int p = 0; p < 4; ++p) {
        int dloc = p * 16 + (t >> 4);                // d-row within 64
        int c8 = (t & 15) << 3;                      // 8 consecutive c per thread
        int gd = dloc >> 2, e = dloc & 3;
        half8 h;
#pragma unroll
        for (int j = 0; j < 8; ++j) {
            int c = c8 + j;
            h[j] = (_Float16)xs[c * 64 + ((gd ^ (c >> 3)) << 2) + e];
        }
        *(half8*)(xTb + (size_t)dloc * A_ + c8) = h;
    }
}

// ---------------- kf: factors left16/rightT16 [32768][16] f16 (cols 10..15 exact 0) ----------------
__global__ __launch_bounds__(256) void kf_factors(const float* __restrict__ x,
                                                  const _Float16* __restrict__ Wf,
                                                  _Float16* __restrict__ left16,
                                                  _Float16* __restrict__ rightT16) {
    int t = threadIdx.x, lane = t & 63, w = t >> 6;
    int quad = lane >> 4, c16 = lane & 15;
    size_t arow0 = (size_t)blockIdx.x * 64 + (size_t)w * 16;  // global a-row (b-major flat)
    const float* xa = x + (arow0 + c16) * D_;
    f32x4 accA = {0.f, 0.f, 0.f, 0.f}, accB = {0.f, 0.f, 0.f, 0.f};
#pragma unroll
    for (int kc = 0; kc < 16; ++kc) {
        float4 v0 = *(const float4*)(xa + kc * 32 + quad * 8);
        float4 v1 = *(const float4*)(xa + kc * 32 + quad * 8 + 4);
        half8 af;
        af[0] = (_Float16)v0.x; af[1] = (_Float16)v0.y; af[2] = (_Float16)v0.z; af[3] = (_Float16)v0.w;
        af[4] = (_Float16)v1.x; af[5] = (_Float16)v1.y; af[6] = (_Float16)v1.z; af[7] = (_Float16)v1.w;
        const half8* wf = (const half8*)(Wf + ((size_t)(kc * 64 + lane)) * 16);
        accA = __builtin_amdgcn_mfma_f32_16x16x32_f16(af, wf[0], accA, 0, 0, 0);
        accB = __builtin_amdgcn_mfma_f32_16x16x32_f16(af, wf[1], accB, 0, 0, 0);
    }
#pragma unroll
    for (int q = 0; q < 4; ++q) {
        size_t grow = arow0 + (size_t)quad * 4 + q;  // C layout: row=quad*4+q (a), col=c16 (r)
        left16[grow * 16 + c16]   = (_Float16)accA[q];
        rightT16[grow * 16 + c16] = (_Float16)accB[q];
    }
}

// ------------- k3: pipelined fused P-recompute + softmax + (P@x) GEMM -------------
// 128a x 256d block tile, 512 thr / 8 waves (2M x 4N, 64a x 64d each), BK=32,
// grid 512 (XCD-swizzled), 1 barrier/iter, 2 blocks/CU, 4 waves/SIMD.
// Interleaved schedule per iter: [P-MFMA(k+1) | DMA(k+1) | bfr(k+2) | bf+af0]
//   fence [af1|mi0|exp0] fence [af2|mi1|exp1] fence [af3|mi2|writePs0]
//   fence [mi3|writePs1|bfr copy].
__global__ __launch_bounds__(512, 4) void k3_attn(const _Float16* __restrict__ xT,
                                                  const _Float16* __restrict__ left16,
                                                  const _Float16* __restrict__ rightT16,
                                                  float* __restrict__ out) {
    __shared__ _Float16 XTl[2][256 * 32];  // [buf][d-local][c-chunk swizzled], rows 64B (32 KB)
    __shared__ _Float16 Ps[2][128 * 40];   // [buf][a-local][c], stride 40 halfs (20.5 KB)
    __shared__ float rowsum[128];
    int t = threadIdx.x, lane = t & 63, w = t >> 6;   // w in [0,8)
    int quad = lane >> 4, c16 = lane & 15;
    int bid = blockIdx.x;
    int combo = (bid & 7) | (((bid >> 7) & 3) << 3);  // (b,nb) pinned per XCD (4 combos/XCD)
    int at = (bid >> 3) & 15;
    int b = combo >> 1, nb = combo & 1;
    int a0 = at << 7, n0 = nb << 8;
    int waveM = w & 1, waveN = w >> 1;                // 2 x 4

    // P fragment: lf8 = left B-operand for this wave's a-rows (quads 2,3 zero pad)
    half8 lf8 = (half8)(_Float16)0.f;
    if (quad < 2) {
        int arow = a0 + w * 16 + c16;
        lf8 = *(const half8*)(left16 + ((size_t)(b << 11) + arow) * 16 + quad * 8);
    }

    f32x4 acc[4][4];
#pragma unroll
    for (int mi = 0; mi < 4; ++mi)
#pragma unroll
        for (int ni = 0; ni < 4; ++ni) acc[mi][ni] = (f32x4){0.f, 0.f, 0.f, 0.f};
    float psum = 0.f;

    const _Float16* xTb = xT + ((size_t)b * D_ + n0) * A_;
    const _Float16* rTb = rightT16 + (size_t)(b << 11) * 16;

    int nloc0 = w * 32 + (lane >> 2);
    int kq = lane & 3;
    int psrow = (w * 16 + c16) * 40;                  // this wave's Ps row offset

    auto dma_tile = [&](int kt, int buf) {
        int c0 = kt << 5;
#pragma unroll
        for (int cc = 0; cc < 2; ++cc) {
            int nl = nloc0 + cc * 16;
            int kqs = kq ^ ((nl >> 1) & 3);
            const _Float16* src = xTb + (size_t)nl * A_ + c0 + kqs * 8;
            _Float16* dst = &XTl[buf][(w * 32 + cc * 16) * 32];
            __builtin_amdgcn_global_load_lds((const __attribute__((address_space(1))) void*)src,
                                             (__attribute__((address_space(3))) void*)dst,
                                             16, 0, 0);
        }
    };
    auto load_bfr = [&](int kt, half8* bfr) {
#pragma unroll
        for (int nh = 0; nh < 2; ++nh) {
            bfr[nh] = (half8)(_Float16)0.f;
            if (quad < 2) {
                int crow = (kt << 5) + nh * 16 + c16;
                bfr[nh] = *(const half8*)(rTb + (size_t)crow * 16 + quad * 8);
            }
        }
    };

    // ---- prologue: P(0) full, DMA(0), bfr for tile 1 ----
    half8 bfr_cur[2], bfr_nxt[2];
    load_bfr(0, bfr_cur);
    dma_tile(0, 0);
    {
        f32x4 zz = {0.f, 0.f, 0.f, 0.f};
        f32x4 p0 = __builtin_amdgcn_mfma_f32_16x16x32_f16(bfr_cur[0], lf8, zz, 0, 0, 0);
        f32x4 p1 = __builtin_amdgcn_mfma_f32_16x16x32_f16(bfr_cur[1], lf8, zz, 0, 0, 0);
        float e0 = fast_exp2(p0[0]), e1 = fast_exp2(p0[1]), e2 = fast_exp2(p0[2]), e3 = fast_exp2(p0[3]);
        float f0 = fast_exp2(p1[0]), f1 = fast_exp2(p1[1]), f2 = fast_exp2(p1[2]), f3 = fast_exp2(p1[3]);
        psum += (e0 + e1) + (e2 + e3) + (f0 + f1) + (f2 + f3);
        half4 pv0, pv1;
        pv0[0] = (_Float16)e0; pv0[1] = (_Float16)e1; pv0[2] = (_Float16)e2; pv0[3] = (_Float16)e3;
        pv1[0] = (_Float16)f0; pv1[1] = (_Float16)f1; pv1[2] = (_Float16)f2; pv1[3] = (_Float16)f3;
        *(half4*)&Ps[0][psrow + quad * 4] = pv0;
        *(half4*)&Ps[0][psrow + 16 + quad * 4] = pv1;
    }
    load_bfr(1, bfr_cur);   // tile 1 operand, consumed at iter 0

    // ---- main loop: iters 0..62 (full), iter 63 peeled (GEMM only) ----
    for (int kt = 0; kt < 63; ++kt) {
        __syncthreads();
        int cb = kt & 1, nx = kt + 1;

        // R0: P-MFMAs for tile nx; issue DMA(nx) + bfr(kt+2); bf + af0 reads
        f32x4 zz = {0.f, 0.f, 0.f, 0.f};
        f32x4 pc0 = __builtin_amdgcn_mfma_f32_16x16x32_f16(bfr_cur[0], lf8, zz, 0, 0, 0);
        f32x4 pc1 = __builtin_amdgcn_mfma_f32_16x16x32_f16(bfr_cur[1], lf8, zz, 0, 0, 0);
        dma_tile(nx, nx & 1);
        {
            int ktn = (kt + 2 < 64) ? kt + 2 : 0;    // branchless tail: dummy reload of tile 0
            load_bfr(ktn, bfr_nxt);
        }
        half8 bf[4];
#pragma unroll
        for (int ni = 0; ni < 4; ++ni) {
            int nr = waveN * 64 + ni * 16 + c16;
            bf[ni] = *(const half8*)&XTl[cb][nr * 32 + ((quad ^ ((nr >> 1) & 3)) << 3)];
        }
        half8 af0 = *(const half8*)&Ps[cb][(waveM * 64 + c16) * 40 + quad * 8];
        SCHED_FENCE();

        // R1: af1 read | mi0 cluster | exp chunk 0
        half8 af1 = *(const half8*)&Ps[cb][(waveM * 64 + 16 + c16) * 40 + quad * 8];
#pragma unroll
        for (int ni = 0; ni < 4; ++ni)
            acc[0][ni] = __builtin_amdgcn_mfma_f32_16x16x32_f16(af0, bf[ni], acc[0][ni], 0, 0, 0);
        float e0 = fast_exp2(pc0[0]), e1 = fast_exp2(pc0[1]);
        float e2 = fast_exp2(pc0[2]), e3 = fast_exp2(pc0[3]);
        psum += (e0 + e1) + (e2 + e3);
        half4 pv0;
        pv0[0] = (_Float16)e0; pv0[1] = (_Float16)e1; pv0[2] = (_Float16)e2; pv0[3] = (_Float16)e3;
        SCHED_FENCE();

        // R2: af2 read | mi1 cluster | exp chunk 1
        half8 af2 = *(const half8*)&Ps[cb][(waveM * 64 + 32 + c16) * 40 + quad * 8];
#pragma unroll
        for (int ni = 0; ni < 4; ++ni)
            acc[1][ni] = __builtin_amdgcn_mfma_f32_16x16x32_f16(af1, bf[ni], acc[1][ni], 0, 0, 0);
        float f0 = fast_exp2(pc1[0]), f1 = fast_exp2(pc1[1]);
        float f2 = fast_exp2(pc1[2]), f3 = fast_exp2(pc1[3]);
        psum += (f0 + f1) + (f2 + f3);
        half4 pv1;
        pv1[0] = (_Float16)f0; pv1[1] = (_Float16)f1; pv1[2] = (_Float16)f2; pv1[3] = (_Float16)f3;
        SCHED_FENCE();

        // R3: af3 read | mi2 cluster | Ps write 0
        half8 af3 = *(const half8*)&Ps[cb][(waveM * 64 + 48 + c16) * 40 + quad * 8];
#pragma unroll
        for (int ni = 0; ni < 4; ++ni)
            acc[2][ni] = __builtin_amdgcn_mfma_f32_16x16x32_f16(af2, bf[ni], acc[2][ni], 0, 0, 0);
        *(half4*)&Ps[nx & 1][psrow + quad * 4] = pv0;
        SCHED_FENCE();

        // R4: mi3 cluster | Ps write 1 | bfr rotate
#pragma unroll
        for (int ni = 0; ni < 4; ++ni)
            acc[3][ni] = __builtin_amdgcn_mfma_f32_16x16x32_f16(af3, bf[ni], acc[3][ni], 0, 0, 0);
        *(half4*)&Ps[nx & 1][psrow + 16 + quad * 4] = pv1;
        bfr_cur[0] = bfr_nxt[0];
        bfr_cur[1] = bfr_nxt[1];
    }

    // ---- peeled iter 63: GEMM only ----
    __syncthreads();
    {
        const int cb = 1;
        half8 bf[4];
#pragma unroll
        for (int ni = 0; ni < 4; ++ni) {
            int nr = waveN * 64 + ni * 16 + c16;
            bf[ni] = *(const half8*)&XTl[cb][nr * 32 + ((quad ^ ((nr >> 1) & 3)) << 3)];
        }
#pragma unroll
        for (int mi = 0; mi < 4; ++mi) {
            half8 af = *(const half8*)&Ps[cb][(waveM * 64 + mi * 16 + c16) * 40 + quad * 8];
#pragma unroll
            for (int ni = 0; ni < 4; ++ni)
                acc[mi][ni] = __builtin_amdgcn_mfma_f32_16x16x32_f16(af, bf[ni], acc[mi][ni], 0, 0, 0);
        }
    }

    // softmax denominators: psum holds partial row-sum for a-row w*16 + c16
    {
        float s = psum;
        s += __shfl_xor(s, 16);
        s += __shfl_xor(s, 32);
        if (quad == 0) rowsum[w * 16 + c16] = s;
    }
    __syncthreads();

    float* ob = out + ((size_t)b * A_ + a0) * D_ + n0;
#pragma unroll
    for (int mi = 0; mi < 4; ++mi) {
#pragma unroll
        for (int q = 0; q < 4; ++q) {
            int ar = waveM * 64 + mi * 16 + quad * 4 + q;
            float sc = 1.0f / rowsum[ar];
#pragma unroll
            for (int ni = 0; ni < 4; ++ni)
                ob[(size_t)ar * D_ + waveN * 64 + ni * 16 + c16] = acc[mi][ni][q] * sc;
        }
    }
}

extern "C" void kernel_launch(void* const* d_in, const int* in_sizes, int n_in,
                              void* d_out, int out_size, void* d_ws, size_t ws_size,
                              hipStream_t stream) {
    const float* x  = (const float*)d_in[0];
    const float* W1 = (const float*)d_in[1];
    const float* W2 = (const float*)d_in[2];
    float* out = (float*)d_out;
    char* ws = (char*)d_ws;
    // ws: xT f16 [16][512][2048] @0 (33,554,432)
    //     left16 f16 [32768][16] @33,554,432 (1,048,576)
    //     rightT16 f16 [32768][16] @34,603,008 (1,048,576)
    //     Wf f16 @35,651,584 (32,768)   total 35,684,352
    _Float16* xT      = (_Float16*)ws;
    _Float16* left16  = (_Float16*)(ws + 33554432);
    _Float16* rightT16= (_Float16*)(ws + 34603008);
    _Float16* Wf      = (_Float16*)(ws + 35651584);

    kw_prep<<<4, 256, 0, stream>>>(W1, W2, Wf);
    kt_transpose<<<2048, 256, 0, stream>>>(x, xT);
    kf_factors<<<512, 256, 0, stream>>>(x, Wf, left16, rightT16);
    k3_attn<<<512, 512, 0, stream>>>(xT, left16, rightT16, out);
}